// Round 7
// baseline (2663.095 us; speedup 1.0000x reference)
//
#include <hip/hip_runtime.h>

#define NVERT 6890
#define NFACE 13776
#define SS 256
#define NPIX (SS*SS)
#define TILE 16
#define NT (SS/TILE)          // 16
#define NTILES (NT*NT)        // 256
#define SENTINEL 0x7F800000FFFFFFFFULL   // zp=+inf, face=0xFFFFFFFF

// ws layout (byte offsets) — base structures < 96 KB; pair list sized at runtime
#define OFF_VB    0u          // vb: NVERT*3*4 = 82,680
#define OFF_CNT   84480u      // cnt: 256*4
#define OFF_OFFS  86016u      // offs: 257*4
#define OFF_CURS  88064u      // cursor: 256*4
#define OFF_PAIRS 90112u      // pairs: u16[cap]  (cap from ws_size; >=500k at 2.09MB)

// ---- exact-rounding helpers (no FMA contraction on the decision path) ----
static __device__ __forceinline__ float edgef(float ax, float ay, float bx, float by,
                                              float px, float py) {
  return __fsub_rn(__fmul_rn(__fsub_rn(ax, px), __fsub_rn(by, py)),
                   __fmul_rn(__fsub_rn(ay, py), __fsub_rn(bx, px)));
}

// shared by count_k / fill_k: padded pixel bbox -> tile range (identical code both passes)
static __device__ __forceinline__ bool face_tiles(const float* __restrict__ vb,
                                                  const int* __restrict__ faces,
                                                  int f, int& tx0, int& tx1,
                                                  int& ty0, int& ty1) {
  int ia = faces[f*3+0], ib = faces[f*3+1], ic = faces[f*3+2];
  float x0 = vb[ia*3+0], y0 = -vb[ia*3+1];
  float x1 = vb[ib*3+0], y1 = -vb[ib*3+1];
  float x2 = vb[ic*3+0], y2 = -vb[ic*3+1];
  float det = edgef(x1, y1, x2, y2, x0, y0);
  if (!(det > 1e-10f)) return false;               // backface / degenerate cull
  float mnx = fminf(x0, fminf(x1, x2)), mxx = fmaxf(x0, fmaxf(x1, x2));
  float mny = fminf(y0, fminf(y1, y2)), mxy = fmaxf(y0, fmaxf(y1, y2));
  int xlo = max((int)floorf((mnx * 256.f + 255.f) * 0.5f) - 2, 0);
  int xhi = min((int)ceilf ((mxx * 256.f + 255.f) * 0.5f) + 2, SS - 1);
  int ylo = max((int)floorf((mny * 256.f + 255.f) * 0.5f) - 2, 0);
  int yhi = min((int)ceilf ((mxy * 256.f + 255.f) * 0.5f) + 2, SS - 1);
  if (xlo > xhi || ylo > yhi) return false;
  tx0 = xlo >> 4; tx1 = xhi >> 4; ty0 = ylo >> 4; ty1 = yhi >> 4;
  return true;
}

// vb layout: per vertex [sx, sy, cz]; also zeroes the tile counters
__global__ __launch_bounds__(256) void vert_k(const float* __restrict__ cam,
                                              const float* __restrict__ verts,
                                              float* __restrict__ vb,
                                              unsigned int* __restrict__ cnt) {
  int i = blockIdx.x * 256 + threadIdx.x;
  if (i < NTILES) cnt[i] = 0u;
  if (i >= NVERT) return;
  float c0 = cam[0], c1 = cam[1], c2 = cam[2];
  float vx = verts[i*3+0], vy = verts[i*3+1], vz = verts[i*3+2];
  vb[i*3+0] = __fmul_rn(c0, __fadd_rn(vx, c1));
  vb[i*3+1] = __fmul_rn(c0, __fadd_rn(vy, c2));
  vb[i*3+2] = __fadd_rn(vz, 2.7320508075688776f);
}

// texture sampling: one thread per (face, sample t in 0..8); writes out_tex only
__global__ __launch_bounds__(256) void tex_k(const float* __restrict__ vb,
                                             const int* __restrict__ faces,
                                             const float* __restrict__ uv,
                                             float* __restrict__ out_tex) {
  int tid = blockIdx.x * 256 + threadIdx.x;
  if (tid >= NFACE * 9) return;
  int f = tid / 9, t = tid - f * 9;
  int ti = t / 3, tj = t - ti * 3;
  float xt = 0.5f * (float)ti;
  float yt = 0.5f * (float)tj;
  int ia = faces[f*3+0], ib = faces[f*3+1], ic = faces[f*3+2];
  float ax = vb[ia*3+0], ay = vb[ia*3+1];
  float bx = vb[ib*3+0], by = vb[ib*3+1];
  float cx = vb[ic*3+0], cy = vb[ic*3+1];
  float sx = (ax - cx) * xt + (bx - cx) * yt + cx;
  float sy = (ay - cy) * xt + (by - cy) * yt + cy;
  sx = fminf(fmaxf(sx, -1.f), 1.f);
  sy = fminf(fmaxf(sy, -1.f), 1.f);
  float gx = (sx + 1.f) * 128.f - 0.5f;
  float gy = (sy + 1.f) * 128.f - 0.5f;
  float x0f = floorf(gx), y0f = floorf(gy);
  float fx = gx - x0f, fy = gy - y0f;
  int x0 = (int)x0f, y0 = (int)y0f;
  float r = 0.f, g = 0.f, b = 0.f;
  #pragma unroll
  for (int dy = 0; dy < 2; ++dy) {
    #pragma unroll
    for (int dx = 0; dx < 2; ++dx) {
      int xi = x0 + dx, yi = y0 + dy;
      if (xi >= 0 && xi < SS && yi >= 0 && yi < SS) {
        float w = (dx ? fx : 1.f - fx) * (dy ? fy : 1.f - fy);
        int base = yi * SS + xi;
        r += w * uv[base];
        g += w * uv[NPIX + base];
        b += w * uv[2 * NPIX + base];
      }
    }
  }
  float* ot = out_tex + f * 81 + ti * 27 + tj * 9;
  #pragma unroll
  for (int kk = 0; kk < 3; ++kk) {
    ot[kk*3+0] = r; ot[kk*3+1] = g; ot[kk*3+2] = b;
  }
}

// pass 1: per-tile face counts
__global__ __launch_bounds__(256) void count_k(const float* __restrict__ vb,
                                               const int* __restrict__ faces,
                                               unsigned int* __restrict__ cnt) {
  int f = blockIdx.x * 256 + threadIdx.x;
  if (f >= NFACE) return;
  int tx0, tx1, ty0, ty1;
  if (!face_tiles(vb, faces, f, tx0, tx1, ty0, ty1)) return;
  for (int ty = ty0; ty <= ty1; ++ty)
    for (int tx = tx0; tx <= tx1; ++tx)
      atomicAdd(&cnt[ty * NT + tx], 1u);
}

// exclusive scan over 256 tile counts -> offs[257]; cursor = copy of offs
__global__ __launch_bounds__(256) void scan256_k(const unsigned int* __restrict__ cnt,
                                                 unsigned int* __restrict__ offs,
                                                 unsigned int* __restrict__ cursor) {
  __shared__ unsigned int b[256];
  int tid = threadIdx.x;
  unsigned int v = cnt[tid];
  b[tid] = v;
  __syncthreads();
  for (int off = 1; off < 256; off <<= 1) {
    unsigned int t = (tid >= off) ? b[tid - off] : 0u;
    __syncthreads();
    b[tid] += t;
    __syncthreads();
  }
  unsigned int excl = b[tid] - v;
  offs[tid] = excl;
  cursor[tid] = excl;
  if (tid == 255) offs[256] = b[255];
}

// pass 2: fill per-tile face lists (u16 face ids; order-independent correctness)
__global__ __launch_bounds__(256) void fill_k(const float* __restrict__ vb,
                                              const int* __restrict__ faces,
                                              unsigned int* __restrict__ cursor,
                                              unsigned short* __restrict__ pairs,
                                              unsigned int cap) {
  int f = blockIdx.x * 256 + threadIdx.x;
  if (f >= NFACE) return;
  int tx0, tx1, ty0, ty1;
  if (!face_tiles(vb, faces, f, tx0, tx1, ty0, ty1)) return;
  for (int ty = ty0; ty <= ty1; ++ty)
    for (int tx = tx0; tx <= tx1; ++tx) {
      unsigned int slot = atomicAdd(&cursor[ty * NT + tx], 1u);
      if (slot < cap) pairs[slot] = (unsigned short)f;
    }
}

// tile rasterizer + fused resolve: 1 block per 16x16 tile, 1 thread per pixel,
// z-buffer in registers, faces staged through LDS in 64-face batches
__global__ __launch_bounds__(256) void tile_k(const float* __restrict__ vb,
                                              const int* __restrict__ faces,
                                              const unsigned int* __restrict__ offs,
                                              const unsigned short* __restrict__ pairs,
                                              unsigned int cap,
                                              const float* __restrict__ out_tex,
                                              float* __restrict__ out_img) {
  __shared__ float lds[64][15];   // 14 used + pad
  int tile = blockIdx.x;
  int tid = threadIdx.x;
  int xx = (tile & (NT - 1)) * TILE + (tid & (TILE - 1));
  int yy = (tile >> 4) * TILE + (tid >> 4);
  float px = (float)(2 * xx + 1 - SS) * (1.0f / 256.0f);   // exact
  float py = (float)(2 * yy + 1 - SS) * (1.0f / 256.0f);
  unsigned int beg = offs[tile];
  unsigned int end = min(offs[tile + 1], cap);
  unsigned long long best = SENTINEL;

  for (unsigned int base = beg; base < end; base += 64) {
    int n = (int)min(64u, end - base);
    if (tid < n) {
      int f = (int)pairs[base + tid];
      int ia = faces[f*3+0], ib = faces[f*3+1], ic = faces[f*3+2];
      float x0 = vb[ia*3+0], y0 = -vb[ia*3+1], z0 = vb[ia*3+2];
      float x1 = vb[ib*3+0], y1 = -vb[ib*3+1], z1 = vb[ib*3+2];
      float x2 = vb[ic*3+0], y2 = -vb[ic*3+1], z2 = vb[ic*3+2];
      float det = edgef(x1, y1, x2, y2, x0, y0);           // >1e-10 (binned)
      float rz0 = (fabsf(z0) > 1e-8f) ? z0 : 1.0f;
      float rz1 = (fabsf(z1) > 1e-8f) ? z1 : 1.0f;
      float rz2 = (fabsf(z2) > 1e-8f) ? z2 : 1.0f;
      float minrz = fminf(fminf(fabsf(rz0), fabsf(rz1)), fabsf(rz2));
      unsigned int flag = (minrz < 0.05f) ? 1u : 0u;
      lds[tid][0] = x0;  lds[tid][1] = y0;
      lds[tid][2] = x1;  lds[tid][3] = y1;
      lds[tid][4] = x2;  lds[tid][5] = y2;
      lds[tid][6] = rz0; lds[tid][7] = rz1; lds[tid][8] = rz2;
      lds[tid][9] = det;
      lds[tid][10] = __fdiv_rn(1.0f, det * rz0);           // approx coeffs
      lds[tid][11] = __fdiv_rn(1.0f, det * rz1);
      lds[tid][12] = __fdiv_rn(1.0f, det * rz2);
      lds[tid][13] = __uint_as_float((unsigned int)f | (flag << 24));
    }
    __syncthreads();
    for (int j = 0; j < n; ++j) {
      float x0 = lds[j][0], y0 = lds[j][1];
      float x1 = lds[j][2], y1 = lds[j][3];
      float x2 = lds[j][4], y2 = lds[j][5];
      float e0 = edgef(x1, y1, x2, y2, px, py);
      float e1 = edgef(x2, y2, x0, y0, px, py);
      float e2 = edgef(x0, y0, x1, y1, px, py);
      if (e0 >= 0.f && e1 >= 0.f && e2 >= 0.f) {
        float inva = __fmaf_rn(e0, lds[j][10],
                     __fmaf_rn(e1, lds[j][11], e2 * lds[j][12]));
        float zc = __uint_as_float((unsigned int)(best >> 32));   // exact current
        unsigned int w13 = __float_as_uint(lds[j][13]);
        bool pass = ((w13 >> 24) != 0u) | (inva * zc > 0.998f) | (fabsf(inva) < 1e-4f);
        if (pass) {
          // exact reference chain (bit-identical decision path)
          float rz0 = lds[j][6], rz1 = lds[j][7], rz2 = lds[j][8], det = lds[j][9];
          float b0 = __fdiv_rn(e0, det);
          float b1 = __fdiv_rn(e1, det);
          float b2 = __fdiv_rn(e2, det);
          float inv = __fadd_rn(__fadd_rn(__fdiv_rn(b0, rz0), __fdiv_rn(b1, rz1)),
                                __fdiv_rn(b2, rz2));
          if (!(fabsf(inv) > 1e-8f)) inv = 1.0f;
          float zp = __fdiv_rn(1.0f, inv);
          if (zp > 0.1f && zp < 25.0f) {
            unsigned long long key =
                ((unsigned long long)__float_as_uint(zp) << 32)
                | (w13 & 0x00FFFFFFu);
            if (key < best) best = key;
          }
        }
      }
    }
    __syncthreads();
  }

  // fused resolve (exact reference chain)
  int p = yy * SS + xx;
  float c0 = 0.f, c1 = 0.f, c2 = 0.f;
  if (best != SENTINEL) {
    int f = (int)(unsigned int)(best & 0xFFFFFFFFULL);
    float bz = __uint_as_float((unsigned int)(best >> 32));
    int ia = faces[f*3+0], ib = faces[f*3+1], ic = faces[f*3+2];
    float x0 = vb[ia*3+0], y0 = -vb[ia*3+1], z0 = vb[ia*3+2];
    float x1 = vb[ib*3+0], y1 = -vb[ib*3+1], z1 = vb[ib*3+2];
    float x2 = vb[ic*3+0], y2 = -vb[ic*3+1], z2 = vb[ic*3+2];
    float det = edgef(x1, y1, x2, y2, x0, y0);
    float e0 = edgef(x1, y1, x2, y2, px, py);
    float e1 = edgef(x2, y2, x0, y0, px, py);
    float e2 = edgef(x0, y0, x1, y1, px, py);
    float b0 = __fdiv_rn(e0, det);
    float b1 = __fdiv_rn(e1, det);
    float b2 = __fdiv_rn(e2, det);
    float rz0 = (fabsf(z0) > 1e-8f) ? z0 : 1.0f;
    float rz1 = (fabsf(z1) > 1e-8f) ? z1 : 1.0f;
    float rz2 = (fabsf(z2) > 1e-8f) ? z2 : 1.0f;
    float w0 = __fmul_rn(__fdiv_rn(b0, rz0), bz);
    float w1 = __fmul_rn(__fdiv_rn(b1, rz1), bz);
    float w2 = __fmul_rn(__fdiv_rn(b2, rz2), bz);
    float pos0 = fminf(fmaxf(w0, 0.f), 1.f) * 2.f;
    float pos1 = fminf(fmaxf(w1, 0.f), 1.f) * 2.f;
    float pos2 = fminf(fmaxf(w2, 0.f), 1.f) * 2.f;
    float i0f = fminf(fmaxf(floorf(pos0), 0.f), 1.f);
    float i1f = fminf(fmaxf(floorf(pos1), 0.f), 1.f);
    float i2f = fminf(fmaxf(floorf(pos2), 0.f), 1.f);
    float fr0 = fminf(fmaxf(__fsub_rn(pos0, i0f), 0.f), 1.f);
    float fr1 = fminf(fmaxf(__fsub_rn(pos1, i1f), 0.f), 1.f);
    float fr2 = fminf(fmaxf(__fsub_rn(pos2, i2f), 0.f), 1.f);
    int i00 = (int)i0f, i01 = (int)i1f;
    #pragma unroll
    for (int d0 = 0; d0 < 2; ++d0) {
      float wa = d0 ? fr0 : __fsub_rn(1.f, fr0);
      #pragma unroll
      for (int d1 = 0; d1 < 2; ++d1) {
        float wb = d1 ? fr1 : __fsub_rn(1.f, fr1);
        int a = min(i00 + d0, 2);
        int b = min(i01 + d1, 2);
        const float* tp = &out_tex[f * 81 + a * 27 + b * 9];  // k=0 slice
        float wab = __fmul_rn(wa, wb);
        #pragma unroll
        for (int d2 = 0; d2 < 2; ++d2) {
          float wc = d2 ? fr2 : __fsub_rn(1.f, fr2);
          float wgt = __fmul_rn(wab, wc);
          c0 = __fadd_rn(c0, __fmul_rn(wgt, tp[0]));
          c1 = __fadd_rn(c1, __fmul_rn(wgt, tp[1]));
          c2 = __fadd_rn(c2, __fmul_rn(wgt, tp[2]));
        }
      }
    }
  }
  out_img[p]          = c0;
  out_img[NPIX + p]   = c1;
  out_img[2*NPIX + p] = c2;
}

extern "C" void kernel_launch(void* const* d_in, const int* in_sizes, int n_in,
                              void* d_out, int out_size, void* d_ws, size_t ws_size,
                              hipStream_t stream) {
  const float* cam   = (const float*)d_in[0];
  const float* verts = (const float*)d_in[1];
  const float* uv    = (const float*)d_in[2];
  const int*   faces = (const int*)d_in[3];
  float* out_img = (float*)d_out;            // (1,3,256,256)
  float* out_tex = (float*)d_out + 3 * NPIX; // (1,NF,3,3,3,3)

  char* ws = (char*)d_ws;
  float* vb                 = (float*)(ws + OFF_VB);
  unsigned int* cnt         = (unsigned int*)(ws + OFF_CNT);
  unsigned int* offs        = (unsigned int*)(ws + OFF_OFFS);
  unsigned int* cursor      = (unsigned int*)(ws + OFF_CURS);
  unsigned short* pairs     = (unsigned short*)(ws + OFF_PAIRS);
  unsigned int cap = (ws_size > OFF_PAIRS + 2)
                   ? (unsigned int)((ws_size - OFF_PAIRS) / 2) : 0u;

  vert_k<<<(NVERT + 255) / 256, 256, 0, stream>>>(cam, verts, vb, cnt);
  tex_k<<<(NFACE * 9 + 255) / 256, 256, 0, stream>>>(vb, faces, uv, out_tex);
  count_k<<<(NFACE + 255) / 256, 256, 0, stream>>>(vb, faces, cnt);
  scan256_k<<<1, 256, 0, stream>>>(cnt, offs, cursor);
  fill_k<<<(NFACE + 255) / 256, 256, 0, stream>>>(vb, faces, cursor, pairs, cap);
  tile_k<<<NTILES, 256, 0, stream>>>(vb, faces, offs, pairs, cap, out_tex, out_img);
}

// Round 9
// 783.665 us; speedup vs baseline: 3.3983x; 3.3983x over previous
//
#include <hip/hip_runtime.h>

#define NVERT 6890
#define NFACE 13776
#define SS 256
#define NPIX (SS*SS)
#define TILE 16
#define NT (SS/TILE)          // 16
#define NTILES (NT*NT)        // 256
#define SENTINEL 0x7F800000FFFFFFFFULL   // zp=+inf, face=0xFFFFFFFF

// ws layout (byte offsets) — total ~970 KB (< 2.09 MB proven safe in round 1)
#define OFF_VB 0u             // vb: NVERT*3*4 = 82,680
#define OFF_FD 84480u         // fd: NFACE*16*4 = 881,664 -> ends at 966,144

// ---- exact-rounding helpers (no FMA contraction on the decision path) ----
static __device__ __forceinline__ float edgef(float ax, float ay, float bx, float by,
                                              float px, float py) {
  return __fsub_rn(__fmul_rn(__fsub_rn(ax, px), __fsub_rn(by, py)),
                   __fmul_rn(__fsub_rn(ay, py), __fsub_rn(bx, px)));
}

// vb layout: per vertex [sx, sy, cz]
__global__ __launch_bounds__(256) void vert_k(const float* __restrict__ cam,
                                              const float* __restrict__ verts,
                                              float* __restrict__ vb) {
  int i = blockIdx.x * 256 + threadIdx.x;
  if (i >= NVERT) return;
  float c0 = cam[0], c1 = cam[1], c2 = cam[2];
  float vx = verts[i*3+0], vy = verts[i*3+1], vz = verts[i*3+2];
  vb[i*3+0] = __fmul_rn(c0, __fadd_rn(vx, c1));
  vb[i*3+1] = __fmul_rn(c0, __fadd_rn(vy, c2));
  vb[i*3+2] = __fadd_rn(vz, 2.7320508075688776f);
}

// texture sampling: one thread per (face, sample t in 0..8); writes out_tex only
__global__ __launch_bounds__(256) void tex_k(const float* __restrict__ vb,
                                             const int* __restrict__ faces,
                                             const float* __restrict__ uv,
                                             float* __restrict__ out_tex) {
  int tid = blockIdx.x * 256 + threadIdx.x;
  if (tid >= NFACE * 9) return;
  int f = tid / 9, t = tid - f * 9;
  int ti = t / 3, tj = t - ti * 3;
  float xt = 0.5f * (float)ti;
  float yt = 0.5f * (float)tj;
  int ia = faces[f*3+0], ib = faces[f*3+1], ic = faces[f*3+2];
  float ax = vb[ia*3+0], ay = vb[ia*3+1];
  float bx = vb[ib*3+0], by = vb[ib*3+1];
  float cx = vb[ic*3+0], cy = vb[ic*3+1];
  float sx = (ax - cx) * xt + (bx - cx) * yt + cx;
  float sy = (ay - cy) * xt + (by - cy) * yt + cy;
  sx = fminf(fmaxf(sx, -1.f), 1.f);
  sy = fminf(fmaxf(sy, -1.f), 1.f);
  float gx = (sx + 1.f) * 128.f - 0.5f;
  float gy = (sy + 1.f) * 128.f - 0.5f;
  float x0f = floorf(gx), y0f = floorf(gy);
  float fx = gx - x0f, fy = gy - y0f;
  int x0 = (int)x0f, y0 = (int)y0f;
  float r = 0.f, g = 0.f, b = 0.f;
  #pragma unroll
  for (int dy = 0; dy < 2; ++dy) {
    #pragma unroll
    for (int dx = 0; dx < 2; ++dx) {
      int xi = x0 + dx, yi = y0 + dy;
      if (xi >= 0 && xi < SS && yi >= 0 && yi < SS) {
        float w = (dx ? fx : 1.f - fx) * (dy ? fy : 1.f - fy);
        int base = yi * SS + xi;
        r += w * uv[base];
        g += w * uv[NPIX + base];
        b += w * uv[2 * NPIX + base];
      }
    }
  }
  float* ot = out_tex + f * 81 + ti * 27 + tj * 9;
  #pragma unroll
  for (int kk = 0; kk < 3; ++kk) {
    ot[kk*3+0] = r; ot[kk*3+1] = g; ot[kk*3+2] = b;
  }
}

// per-face setup: 64B record [x0,y0,x1,y1, x2,y2,rz0,rz1, rz2,det,c0,c1, c2,idflag,tilepack,-]
__global__ __launch_bounds__(256) void setup_k(const float* __restrict__ vb,
                                               const int* __restrict__ faces,
                                               float* __restrict__ fd) {
  int f = blockIdx.x * 256 + threadIdx.x;
  if (f >= NFACE) return;
  float* fp = fd + (size_t)f * 16;
  int ia = faces[f*3+0], ib = faces[f*3+1], ic = faces[f*3+2];
  float x0 = vb[ia*3+0], y0 = -vb[ia*3+1], z0 = vb[ia*3+2];
  float x1 = vb[ib*3+0], y1 = -vb[ib*3+1], z1 = vb[ib*3+2];
  float x2 = vb[ic*3+0], y2 = -vb[ic*3+1], z2 = vb[ic*3+2];
  float det = edgef(x1, y1, x2, y2, x0, y0);
  unsigned int tilepack = 0x000000FFu;                   // tx0=255 > tx1=0 -> never overlaps
  if (det > 1e-10f) {
    float mnx = fminf(x0, fminf(x1, x2)), mxx = fmaxf(x0, fmaxf(x1, x2));
    float mny = fminf(y0, fminf(y1, y2)), mxy = fmaxf(y0, fmaxf(y1, y2));
    int xlo = max((int)floorf((mnx * 256.f + 255.f) * 0.5f) - 2, 0);
    int xhi = min((int)ceilf ((mxx * 256.f + 255.f) * 0.5f) + 2, SS - 1);
    int ylo = max((int)floorf((mny * 256.f + 255.f) * 0.5f) - 2, 0);
    int yhi = min((int)ceilf ((mxy * 256.f + 255.f) * 0.5f) + 2, SS - 1);
    if (xlo <= xhi && ylo <= yhi)
      tilepack = (unsigned int)(xlo >> 4) | ((unsigned int)(ylo >> 4) << 8)
               | ((unsigned int)(xhi >> 4) << 16) | ((unsigned int)(yhi >> 4) << 24);
  }
  float rz0 = (fabsf(z0) > 1e-8f) ? z0 : 1.0f;
  float rz1 = (fabsf(z1) > 1e-8f) ? z1 : 1.0f;
  float rz2 = (fabsf(z2) > 1e-8f) ? z2 : 1.0f;
  float minrz = fminf(fminf(fabsf(rz0), fabsf(rz1)), fabsf(rz2));
  unsigned int flag = (minrz < 0.05f) ? 1u : 0u;
  fp[0] = x0;  fp[1] = y0;  fp[2] = x1;  fp[3] = y1;
  fp[4] = x2;  fp[5] = y2;  fp[6] = rz0; fp[7] = rz1;
  fp[8] = rz2; fp[9] = det;
  fp[10] = __fdiv_rn(1.0f, det * rz0);                   // approx coeffs
  fp[11] = __fdiv_rn(1.0f, det * rz1);
  fp[12] = __fdiv_rn(1.0f, det * rz2);
  fp[13] = __uint_as_float((unsigned int)f | (flag << 24));
  fp[14] = __uint_as_float(tilepack);
  fp[15] = 0.f;
}

// fused bin+rasterize+resolve: 1 block per 16x16 tile, 1 thread per pixel.
// Streams all face records in 256-face chunks, LDS-compacts tile hits,
// z-buffer in registers. Decision chain bit-identical to reference.
__global__ __launch_bounds__(256) void tile_k(const float* __restrict__ vb,
                                              const int* __restrict__ faces,
                                              const float* __restrict__ fd,
                                              const float* __restrict__ out_tex,
                                              float* __restrict__ out_img) {
  __shared__ float rec[256][15];     // 14 used + pad
  __shared__ unsigned int cnt_s;
  int tile = blockIdx.x;
  int tid = threadIdx.x;
  int tx = tile & (NT - 1), ty = tile >> 4;
  int xx = tx * TILE + (tid & (TILE - 1));
  int yy = ty * TILE + (tid >> 4);
  float px = (float)(2 * xx + 1 - SS) * (1.0f / 256.0f);   // exact
  float py = (float)(2 * yy + 1 - SS) * (1.0f / 256.0f);
  unsigned long long best = SENTINEL;

  for (int base = 0; base < NFACE; base += 256) {
    __syncthreads();                       // previous consume done
    if (tid == 0) cnt_s = 0;
    __syncthreads();
    int f = base + tid;
    if (f < NFACE) {
      const float4* fr = (const float4*)(fd + (size_t)f * 16);
      float4 A = fr[0];                    // x0,y0,x1,y1
      float4 B = fr[1];                    // x2,y2,rz0,rz1
      float4 C = fr[2];                    // rz2,det,c0,c1
      float4 D = fr[3];                    // c2,idflag,tilepack,-
      unsigned int tp = __float_as_uint(D.z);
      int tx0 = (int)(tp & 255u),         ty0 = (int)((tp >> 8) & 255u);
      int tx1 = (int)((tp >> 16) & 255u), ty1 = (int)(tp >> 24);
      if (tx >= tx0 && tx <= tx1 && ty >= ty0 && ty <= ty1) {
        unsigned int slot = atomicAdd(&cnt_s, 1u);   // LDS atomic
        rec[slot][0]  = A.x; rec[slot][1]  = A.y;
        rec[slot][2]  = A.z; rec[slot][3]  = A.w;
        rec[slot][4]  = B.x; rec[slot][5]  = B.y;
        rec[slot][6]  = B.z; rec[slot][7]  = B.w;
        rec[slot][8]  = C.x; rec[slot][9]  = C.y;
        rec[slot][10] = C.z; rec[slot][11] = C.w;
        rec[slot][12] = D.x; rec[slot][13] = D.y;
      }
    }
    __syncthreads();
    int m = (int)cnt_s;
    for (int j = 0; j < m; ++j) {
      float x0 = rec[j][0], y0 = rec[j][1];
      float x1 = rec[j][2], y1 = rec[j][3];
      float x2 = rec[j][4], y2 = rec[j][5];
      float e0 = edgef(x1, y1, x2, y2, px, py);
      float e1 = edgef(x2, y2, x0, y0, px, py);
      float e2 = edgef(x0, y0, x1, y1, px, py);
      if (e0 >= 0.f && e1 >= 0.f && e2 >= 0.f) {
        float inva = __fmaf_rn(e0, rec[j][10],
                     __fmaf_rn(e1, rec[j][11], e2 * rec[j][12]));
        float zc = __uint_as_float((unsigned int)(best >> 32));   // exact current
        unsigned int w13 = __float_as_uint(rec[j][13]);
        bool pass = ((w13 >> 24) != 0u) | (inva * zc > 0.998f) | (fabsf(inva) < 1e-4f);
        if (pass) {
          // exact reference chain (bit-identical decision path)
          float rz0 = rec[j][6], rz1 = rec[j][7], rz2 = rec[j][8], det = rec[j][9];
          float b0 = __fdiv_rn(e0, det);
          float b1 = __fdiv_rn(e1, det);
          float b2 = __fdiv_rn(e2, det);
          float inv = __fadd_rn(__fadd_rn(__fdiv_rn(b0, rz0), __fdiv_rn(b1, rz1)),
                                __fdiv_rn(b2, rz2));
          if (!(fabsf(inv) > 1e-8f)) inv = 1.0f;
          float zp = __fdiv_rn(1.0f, inv);
          if (zp > 0.1f && zp < 25.0f) {
            unsigned long long key =
                ((unsigned long long)__float_as_uint(zp) << 32)
                | (w13 & 0x00FFFFFFu);
            if (key < best) best = key;
          }
        }
      }
    }
  }

  // fused resolve (exact reference chain)
  int p = yy * SS + xx;
  float c0 = 0.f, c1 = 0.f, c2 = 0.f;
  if (best != SENTINEL) {
    int f = (int)(unsigned int)(best & 0xFFFFFFFFULL);
    float bz = __uint_as_float((unsigned int)(best >> 32));
    int ia = faces[f*3+0], ib = faces[f*3+1], ic = faces[f*3+2];
    float x0 = vb[ia*3+0], y0 = -vb[ia*3+1], z0 = vb[ia*3+2];
    float x1 = vb[ib*3+0], y1 = -vb[ib*3+1], z1 = vb[ib*3+2];
    float x2 = vb[ic*3+0], y2 = -vb[ic*3+1], z2 = vb[ic*3+2];
    float det = edgef(x1, y1, x2, y2, x0, y0);
    float e0 = edgef(x1, y1, x2, y2, px, py);
    float e1 = edgef(x2, y2, x0, y0, px, py);
    float e2 = edgef(x0, y0, x1, y1, px, py);
    float b0 = __fdiv_rn(e0, det);
    float b1 = __fdiv_rn(e1, det);
    float b2 = __fdiv_rn(e2, det);
    float rz0 = (fabsf(z0) > 1e-8f) ? z0 : 1.0f;
    float rz1 = (fabsf(z1) > 1e-8f) ? z1 : 1.0f;
    float rz2 = (fabsf(z2) > 1e-8f) ? z2 : 1.0f;
    float w0 = __fmul_rn(__fdiv_rn(b0, rz0), bz);
    float w1 = __fmul_rn(__fdiv_rn(b1, rz1), bz);
    float w2 = __fmul_rn(__fdiv_rn(b2, rz2), bz);
    float pos0 = fminf(fmaxf(w0, 0.f), 1.f) * 2.f;
    float pos1 = fminf(fmaxf(w1, 0.f), 1.f) * 2.f;
    float pos2 = fminf(fmaxf(w2, 0.f), 1.f) * 2.f;
    float i0f = fminf(fmaxf(floorf(pos0), 0.f), 1.f);
    float i1f = fminf(fmaxf(floorf(pos1), 0.f), 1.f);
    float i2f = fminf(fmaxf(floorf(pos2), 0.f), 1.f);
    float fr0 = fminf(fmaxf(__fsub_rn(pos0, i0f), 0.f), 1.f);
    float fr1 = fminf(fmaxf(__fsub_rn(pos1, i1f), 0.f), 1.f);
    float fr2 = fminf(fmaxf(__fsub_rn(pos2, i2f), 0.f), 1.f);
    int i00 = (int)i0f, i01 = (int)i1f;
    #pragma unroll
    for (int d0 = 0; d0 < 2; ++d0) {
      float wa = d0 ? fr0 : __fsub_rn(1.f, fr0);
      #pragma unroll
      for (int d1 = 0; d1 < 2; ++d1) {
        float wb = d1 ? fr1 : __fsub_rn(1.f, fr1);
        int a = min(i00 + d0, 2);
        int b = min(i01 + d1, 2);
        const float* tp = &out_tex[f * 81 + a * 27 + b * 9];  // k=0 slice
        float wab = __fmul_rn(wa, wb);
        #pragma unroll
        for (int d2 = 0; d2 < 2; ++d2) {
          float wc = d2 ? fr2 : __fsub_rn(1.f, fr2);
          float wgt = __fmul_rn(wab, wc);
          c0 = __fadd_rn(c0, __fmul_rn(wgt, tp[0]));
          c1 = __fadd_rn(c1, __fmul_rn(wgt, tp[1]));
          c2 = __fadd_rn(c2, __fmul_rn(wgt, tp[2]));
        }
      }
    }
  }
  out_img[p]          = c0;
  out_img[NPIX + p]   = c1;
  out_img[2*NPIX + p] = c2;
}

extern "C" void kernel_launch(void* const* d_in, const int* in_sizes, int n_in,
                              void* d_out, int out_size, void* d_ws, size_t ws_size,
                              hipStream_t stream) {
  const float* cam   = (const float*)d_in[0];
  const float* verts = (const float*)d_in[1];
  const float* uv    = (const float*)d_in[2];
  const int*   faces = (const int*)d_in[3];
  float* out_img = (float*)d_out;            // (1,3,256,256)
  float* out_tex = (float*)d_out + 3 * NPIX; // (1,NF,3,3,3,3)

  char* ws = (char*)d_ws;
  float* vb = (float*)(ws + OFF_VB);
  float* fd = (float*)(ws + OFF_FD);

  vert_k<<<(NVERT + 255) / 256, 256, 0, stream>>>(cam, verts, vb);
  tex_k<<<(NFACE * 9 + 255) / 256, 256, 0, stream>>>(vb, faces, uv, out_tex);
  setup_k<<<(NFACE + 255) / 256, 256, 0, stream>>>(vb, faces, fd);
  tile_k<<<NTILES, 256, 0, stream>>>(vb, faces, fd, out_tex, out_img);
}

// Round 10
// 265.273 us; speedup vs baseline: 10.0391x; 2.9542x over previous
//
#include <hip/hip_runtime.h>

#define NVERT 6890
#define NFACE 13776
#define SS 256
#define NPIX (SS*SS)
#define TILE 16
#define NT (SS/TILE)          // 16
#define NTILES (NT*NT)        // 256
#define SPLIT 8               // blocks per tile (face-stream segments)
#define SEGLEN 1722           // NFACE / SPLIT (exact)
#define SENTINEL 0x7F800000FFFFFFFFULL   // zp=+inf, face=0xFFFFFFFF

// ws layout (byte offsets) — total ~1.49 MB (< 2.09 MB proven safe in round 1)
#define OFF_KEYS 0u           // keys: NPIX*8 = 524,288
#define OFF_VB   524288u      // vb: NVERT*3*4 = 82,680
#define OFF_FD   607232u      // fd: NFACE*16*4 = 881,664 -> ends at 1,488,896

// ---- exact-rounding helpers (no FMA contraction on the decision path) ----
static __device__ __forceinline__ float edgef(float ax, float ay, float bx, float by,
                                              float px, float py) {
  return __fsub_rn(__fmul_rn(__fsub_rn(ax, px), __fsub_rn(by, py)),
                   __fmul_rn(__fsub_rn(ay, py), __fsub_rn(bx, px)));
}

// vb layout: per vertex [sx, sy, cz]
__global__ __launch_bounds__(256) void vert_k(const float* __restrict__ cam,
                                              const float* __restrict__ verts,
                                              float* __restrict__ vb) {
  int i = blockIdx.x * 256 + threadIdx.x;
  if (i >= NVERT) return;
  float c0 = cam[0], c1 = cam[1], c2 = cam[2];
  float vx = verts[i*3+0], vy = verts[i*3+1], vz = verts[i*3+2];
  vb[i*3+0] = __fmul_rn(c0, __fadd_rn(vx, c1));
  vb[i*3+1] = __fmul_rn(c0, __fadd_rn(vy, c2));
  vb[i*3+2] = __fadd_rn(vz, 2.7320508075688776f);
}

__global__ __launch_bounds__(256) void init_k(unsigned long long* __restrict__ keys) {
  int p = blockIdx.x * 256 + threadIdx.x;
  if (p < NPIX) keys[p] = SENTINEL;
}

// texture sampling: one thread per (face, sample t in 0..8); writes out_tex only
__global__ __launch_bounds__(256) void tex_k(const float* __restrict__ vb,
                                             const int* __restrict__ faces,
                                             const float* __restrict__ uv,
                                             float* __restrict__ out_tex) {
  int tid = blockIdx.x * 256 + threadIdx.x;
  if (tid >= NFACE * 9) return;
  int f = tid / 9, t = tid - f * 9;
  int ti = t / 3, tj = t - ti * 3;
  float xt = 0.5f * (float)ti;
  float yt = 0.5f * (float)tj;
  int ia = faces[f*3+0], ib = faces[f*3+1], ic = faces[f*3+2];
  float ax = vb[ia*3+0], ay = vb[ia*3+1];
  float bx = vb[ib*3+0], by = vb[ib*3+1];
  float cx = vb[ic*3+0], cy = vb[ic*3+1];
  float sx = (ax - cx) * xt + (bx - cx) * yt + cx;
  float sy = (ay - cy) * xt + (by - cy) * yt + cy;
  sx = fminf(fmaxf(sx, -1.f), 1.f);
  sy = fminf(fmaxf(sy, -1.f), 1.f);
  float gx = (sx + 1.f) * 128.f - 0.5f;
  float gy = (sy + 1.f) * 128.f - 0.5f;
  float x0f = floorf(gx), y0f = floorf(gy);
  float fx = gx - x0f, fy = gy - y0f;
  int x0 = (int)x0f, y0 = (int)y0f;
  float r = 0.f, g = 0.f, b = 0.f;
  #pragma unroll
  for (int dy = 0; dy < 2; ++dy) {
    #pragma unroll
    for (int dx = 0; dx < 2; ++dx) {
      int xi = x0 + dx, yi = y0 + dy;
      if (xi >= 0 && xi < SS && yi >= 0 && yi < SS) {
        float w = (dx ? fx : 1.f - fx) * (dy ? fy : 1.f - fy);
        int base = yi * SS + xi;
        r += w * uv[base];
        g += w * uv[NPIX + base];
        b += w * uv[2 * NPIX + base];
      }
    }
  }
  float* ot = out_tex + f * 81 + ti * 27 + tj * 9;
  #pragma unroll
  for (int kk = 0; kk < 3; ++kk) {
    ot[kk*3+0] = r; ot[kk*3+1] = g; ot[kk*3+2] = b;
  }
}

// per-face setup: 64B record [x0,y0,x1,y1, x2,y2,rz0,rz1, rz2,det,c0,c1, c2,idflag,tilepack,-]
__global__ __launch_bounds__(256) void setup_k(const float* __restrict__ vb,
                                               const int* __restrict__ faces,
                                               float* __restrict__ fd) {
  int f = blockIdx.x * 256 + threadIdx.x;
  if (f >= NFACE) return;
  float* fp = fd + (size_t)f * 16;
  int ia = faces[f*3+0], ib = faces[f*3+1], ic = faces[f*3+2];
  float x0 = vb[ia*3+0], y0 = -vb[ia*3+1], z0 = vb[ia*3+2];
  float x1 = vb[ib*3+0], y1 = -vb[ib*3+1], z1 = vb[ib*3+2];
  float x2 = vb[ic*3+0], y2 = -vb[ic*3+1], z2 = vb[ic*3+2];
  float det = edgef(x1, y1, x2, y2, x0, y0);
  unsigned int tilepack = 0x000000FFu;                   // tx0=255 > tx1=0 -> never overlaps
  if (det > 1e-10f) {
    float mnx = fminf(x0, fminf(x1, x2)), mxx = fmaxf(x0, fmaxf(x1, x2));
    float mny = fminf(y0, fminf(y1, y2)), mxy = fmaxf(y0, fmaxf(y1, y2));
    int xlo = max((int)floorf((mnx * 256.f + 255.f) * 0.5f) - 2, 0);
    int xhi = min((int)ceilf ((mxx * 256.f + 255.f) * 0.5f) + 2, SS - 1);
    int ylo = max((int)floorf((mny * 256.f + 255.f) * 0.5f) - 2, 0);
    int yhi = min((int)ceilf ((mxy * 256.f + 255.f) * 0.5f) + 2, SS - 1);
    if (xlo <= xhi && ylo <= yhi)
      tilepack = (unsigned int)(xlo >> 4) | ((unsigned int)(ylo >> 4) << 8)
               | ((unsigned int)(xhi >> 4) << 16) | ((unsigned int)(yhi >> 4) << 24);
  }
  float rz0 = (fabsf(z0) > 1e-8f) ? z0 : 1.0f;
  float rz1 = (fabsf(z1) > 1e-8f) ? z1 : 1.0f;
  float rz2 = (fabsf(z2) > 1e-8f) ? z2 : 1.0f;
  float minrz = fminf(fminf(fabsf(rz0), fabsf(rz1)), fabsf(rz2));
  unsigned int flag = (minrz < 0.05f) ? 1u : 0u;
  fp[0] = x0;  fp[1] = y0;  fp[2] = x1;  fp[3] = y1;
  fp[4] = x2;  fp[5] = y2;  fp[6] = rz0; fp[7] = rz1;
  fp[8] = rz2; fp[9] = det;
  fp[10] = __fdiv_rn(1.0f, det * rz0);                   // approx coeffs
  fp[11] = __fdiv_rn(1.0f, det * rz1);
  fp[12] = __fdiv_rn(1.0f, det * rz2);
  fp[13] = __uint_as_float((unsigned int)f | (flag << 24));
  fp[14] = __uint_as_float(tilepack);
  fp[15] = 0.f;
}

// fused bin+rasterize: SPLIT blocks per tile, each streams a face-range,
// z-key in registers, one atomicMin per pixel at the end.
__global__ __launch_bounds__(256) void tile_k(const float* __restrict__ fd,
                                              unsigned long long* __restrict__ keys) {
  __shared__ float rec[256][15];     // 14 used + pad
  __shared__ unsigned int cnt_s;
  int tile = blockIdx.x & (NTILES - 1);
  int seg  = blockIdx.x >> 8;        // 0..SPLIT-1
  int tid = threadIdx.x;
  int tx = tile & (NT - 1), ty = tile >> 4;
  int xx = tx * TILE + (tid & (TILE - 1));
  int yy = ty * TILE + (tid >> 4);
  float px = (float)(2 * xx + 1 - SS) * (1.0f / 256.0f);   // exact
  float py = (float)(2 * yy + 1 - SS) * (1.0f / 256.0f);
  unsigned long long best = SENTINEL;
  int fbeg = seg * SEGLEN;
  int fend = min(fbeg + SEGLEN, NFACE);

  for (int base = fbeg; base < fend; base += 256) {
    __syncthreads();                       // previous consume done
    if (tid == 0) cnt_s = 0;
    __syncthreads();
    int f = base + tid;
    if (f < fend) {
      const float4* fr = (const float4*)(fd + (size_t)f * 16);
      float4 A = fr[0];                    // x0,y0,x1,y1
      float4 B = fr[1];                    // x2,y2,rz0,rz1
      float4 C = fr[2];                    // rz2,det,c0,c1
      float4 D = fr[3];                    // c2,idflag,tilepack,-
      unsigned int tp = __float_as_uint(D.z);
      int tx0 = (int)(tp & 255u),         ty0 = (int)((tp >> 8) & 255u);
      int tx1 = (int)((tp >> 16) & 255u), ty1 = (int)(tp >> 24);
      if (tx >= tx0 && tx <= tx1 && ty >= ty0 && ty <= ty1) {
        unsigned int slot = atomicAdd(&cnt_s, 1u);   // LDS atomic
        rec[slot][0]  = A.x; rec[slot][1]  = A.y;
        rec[slot][2]  = A.z; rec[slot][3]  = A.w;
        rec[slot][4]  = B.x; rec[slot][5]  = B.y;
        rec[slot][6]  = B.z; rec[slot][7]  = B.w;
        rec[slot][8]  = C.x; rec[slot][9]  = C.y;
        rec[slot][10] = C.z; rec[slot][11] = C.w;
        rec[slot][12] = D.x; rec[slot][13] = D.y;
      }
    }
    __syncthreads();
    int m = (int)cnt_s;
    for (int j = 0; j < m; ++j) {
      float x0 = rec[j][0], y0 = rec[j][1];
      float x1 = rec[j][2], y1 = rec[j][3];
      float x2 = rec[j][4], y2 = rec[j][5];
      float e0 = edgef(x1, y1, x2, y2, px, py);
      float e1 = edgef(x2, y2, x0, y0, px, py);
      float e2 = edgef(x0, y0, x1, y1, px, py);
      if (e0 >= 0.f && e1 >= 0.f && e2 >= 0.f) {
        float inva = __fmaf_rn(e0, rec[j][10],
                     __fmaf_rn(e1, rec[j][11], e2 * rec[j][12]));
        float zc = __uint_as_float((unsigned int)(best >> 32));   // local best (conservative)
        unsigned int w13 = __float_as_uint(rec[j][13]);
        bool pass = ((w13 >> 24) != 0u) | (inva * zc > 0.998f) | (fabsf(inva) < 1e-4f);
        if (pass) {
          // exact reference chain (bit-identical decision path)
          float rz0 = rec[j][6], rz1 = rec[j][7], rz2 = rec[j][8], det = rec[j][9];
          float b0 = __fdiv_rn(e0, det);
          float b1 = __fdiv_rn(e1, det);
          float b2 = __fdiv_rn(e2, det);
          float inv = __fadd_rn(__fadd_rn(__fdiv_rn(b0, rz0), __fdiv_rn(b1, rz1)),
                                __fdiv_rn(b2, rz2));
          if (!(fabsf(inv) > 1e-8f)) inv = 1.0f;
          float zp = __fdiv_rn(1.0f, inv);
          if (zp > 0.1f && zp < 25.0f) {
            unsigned long long key =
                ((unsigned long long)__float_as_uint(zp) << 32)
                | (w13 & 0x00FFFFFFu);
            if (key < best) best = key;
          }
        }
      }
    }
  }
  if (best != SENTINEL) {
    int p = yy * SS + xx;
    if (best < keys[p]) atomicMin(&keys[p], best);   // monotone merge
  }
}

// resolve: one thread per pixel -> images output (exact reference chain)
__global__ __launch_bounds__(256) void resolve_k(const float* __restrict__ vb,
                                                 const int* __restrict__ faces,
                                                 const unsigned long long* __restrict__ keys,
                                                 const float* __restrict__ out_tex,
                                                 float* __restrict__ out_img) {
  int p = blockIdx.x * 256 + threadIdx.x;
  if (p >= NPIX) return;
  unsigned long long k = keys[p];
  float c0 = 0.f, c1 = 0.f, c2 = 0.f;
  if (k != SENTINEL) {
    int f = (int)(unsigned int)(k & 0x00FFFFFFULL);
    float bz = __uint_as_float((unsigned int)(k >> 32));
    int xx = p & (SS - 1), yy = p >> 8;
    float px = (float)(2 * xx + 1 - SS) * (1.0f / 256.0f);
    float py = (float)(2 * yy + 1 - SS) * (1.0f / 256.0f);
    int ia = faces[f*3+0], ib = faces[f*3+1], ic = faces[f*3+2];
    float x0 = vb[ia*3+0], y0 = -vb[ia*3+1], z0 = vb[ia*3+2];
    float x1 = vb[ib*3+0], y1 = -vb[ib*3+1], z1 = vb[ib*3+2];
    float x2 = vb[ic*3+0], y2 = -vb[ic*3+1], z2 = vb[ic*3+2];
    float det = edgef(x1, y1, x2, y2, x0, y0);
    float e0 = edgef(x1, y1, x2, y2, px, py);
    float e1 = edgef(x2, y2, x0, y0, px, py);
    float e2 = edgef(x0, y0, x1, y1, px, py);
    float b0 = __fdiv_rn(e0, det);
    float b1 = __fdiv_rn(e1, det);
    float b2 = __fdiv_rn(e2, det);
    float rz0 = (fabsf(z0) > 1e-8f) ? z0 : 1.0f;
    float rz1 = (fabsf(z1) > 1e-8f) ? z1 : 1.0f;
    float rz2 = (fabsf(z2) > 1e-8f) ? z2 : 1.0f;
    float w0 = __fmul_rn(__fdiv_rn(b0, rz0), bz);
    float w1 = __fmul_rn(__fdiv_rn(b1, rz1), bz);
    float w2 = __fmul_rn(__fdiv_rn(b2, rz2), bz);
    float pos0 = fminf(fmaxf(w0, 0.f), 1.f) * 2.f;
    float pos1 = fminf(fmaxf(w1, 0.f), 1.f) * 2.f;
    float pos2 = fminf(fmaxf(w2, 0.f), 1.f) * 2.f;
    float i0f = fminf(fmaxf(floorf(pos0), 0.f), 1.f);
    float i1f = fminf(fmaxf(floorf(pos1), 0.f), 1.f);
    float i2f = fminf(fmaxf(floorf(pos2), 0.f), 1.f);
    float fr0 = fminf(fmaxf(__fsub_rn(pos0, i0f), 0.f), 1.f);
    float fr1 = fminf(fmaxf(__fsub_rn(pos1, i1f), 0.f), 1.f);
    float fr2 = fminf(fmaxf(__fsub_rn(pos2, i2f), 0.f), 1.f);
    int i00 = (int)i0f, i01 = (int)i1f;
    #pragma unroll
    for (int d0 = 0; d0 < 2; ++d0) {
      float wa = d0 ? fr0 : __fsub_rn(1.f, fr0);
      #pragma unroll
      for (int d1 = 0; d1 < 2; ++d1) {
        float wb = d1 ? fr1 : __fsub_rn(1.f, fr1);
        int a = min(i00 + d0, 2);
        int b = min(i01 + d1, 2);
        const float* tp = &out_tex[f * 81 + a * 27 + b * 9];  // k=0 slice
        float wab = __fmul_rn(wa, wb);
        #pragma unroll
        for (int d2 = 0; d2 < 2; ++d2) {
          float wc = d2 ? fr2 : __fsub_rn(1.f, fr2);
          float wgt = __fmul_rn(wab, wc);
          c0 = __fadd_rn(c0, __fmul_rn(wgt, tp[0]));
          c1 = __fadd_rn(c1, __fmul_rn(wgt, tp[1]));
          c2 = __fadd_rn(c2, __fmul_rn(wgt, tp[2]));
        }
      }
    }
  }
  out_img[p]          = c0;
  out_img[NPIX + p]   = c1;
  out_img[2*NPIX + p] = c2;
}

extern "C" void kernel_launch(void* const* d_in, const int* in_sizes, int n_in,
                              void* d_out, int out_size, void* d_ws, size_t ws_size,
                              hipStream_t stream) {
  const float* cam   = (const float*)d_in[0];
  const float* verts = (const float*)d_in[1];
  const float* uv    = (const float*)d_in[2];
  const int*   faces = (const int*)d_in[3];
  float* out_img = (float*)d_out;            // (1,3,256,256)
  float* out_tex = (float*)d_out + 3 * NPIX; // (1,NF,3,3,3,3)

  char* ws = (char*)d_ws;
  unsigned long long* keys = (unsigned long long*)(ws + OFF_KEYS);
  float* vb = (float*)(ws + OFF_VB);
  float* fd = (float*)(ws + OFF_FD);

  vert_k<<<(NVERT + 255) / 256, 256, 0, stream>>>(cam, verts, vb);
  init_k<<<NPIX / 256, 256, 0, stream>>>(keys);
  tex_k<<<(NFACE * 9 + 255) / 256, 256, 0, stream>>>(vb, faces, uv, out_tex);
  setup_k<<<(NFACE + 255) / 256, 256, 0, stream>>>(vb, faces, fd);
  tile_k<<<NTILES * SPLIT, 256, 0, stream>>>(fd, keys);
  resolve_k<<<NPIX / 256, 256, 0, stream>>>(vb, faces, keys, out_tex, out_img);
}